// Round 6
// baseline (146.648 us; speedup 1.0000x reference)
//
#include <hip/hip_runtime.h>
#include <hip/hip_bf16.h>

#define NB 16
#define LC 2048
#define LQ 256
#define DD 256
#define NEGINF -1e30f

typedef __attribute__((ext_vector_type(8))) short bf16x8;
typedef __attribute__((ext_vector_type(4))) float f32x4;

#define MFMA16(a, b, c) __builtin_amdgcn_mfma_f32_16x16x32_bf16((a), (b), (c), 0, 0, 0)

typedef const unsigned int __attribute__((address_space(1))) glb_u32;
typedef unsigned int __attribute__((address_space(3))) lds_u32;

__device__ __forceinline__ void gload_lds16(const void* g, void* l) {
    __builtin_amdgcn_global_load_lds((glb_u32*)g, (lds_u32*)l, 16, 0, 0);
}

__device__ __forceinline__ short f2b(float x) {
    unsigned u = __float_as_uint(x);
    unsigned r = (u + 0x7fffu + ((u >> 16) & 1u)) >> 16;
    return (short)r;
}
__device__ __forceinline__ float b2f(short s) {
    return __uint_as_float(((unsigned)(unsigned short)s) << 16);
}

// ---------- prep_c: one pass over c -> c16 [i][d], cT16 [d][i], s0c row-dots ----
__global__ __launch_bounds__(256) void prep_c(
        const float* __restrict__ c, const float* __restrict__ c_w,
        short* __restrict__ c16, short* __restrict__ cT16,
        float* __restrict__ s0c) {
    __shared__ float T[64][65];
    int b = blockIdx.y, i0 = blockIdx.x * 64, t = threadIdx.x;
    int dd = t & 63, rg = t >> 6;
    float acc[16];
    #pragma unroll
    for (int i = 0; i < 16; ++i) acc[i] = 0.f;
    for (int dc = 0; dc < 4; ++dc) {
        float cwv = c_w[dc * 64 + dd];
        #pragma unroll
        for (int rr = 0; rr < 16; ++rr) {
            int r = rg + 4 * rr;
            float v = c[((size_t)b * LC + i0 + r) * DD + dc * 64 + dd];
            c16[((size_t)b * LC + i0 + r) * DD + dc * 64 + dd] = f2b(v);
            acc[rr] += v * cwv;
            T[dd][r] = v;
        }
        __syncthreads();
        int jj = t & 63;
        for (int dw = t >> 6; dw < 64; dw += 4)
            cT16[((size_t)b * DD + dc * 64 + dw) * (size_t)LC + i0 + jj] =
                f2b(T[dw][jj]);
        __syncthreads();
    }
    #pragma unroll
    for (int rr = 0; rr < 16; ++rr) {
        float s = acc[rr];
        #pragma unroll
        for (int o = 32; o > 0; o >>= 1) s += __shfl_xor(s, o, 64);
        if (dd == 0) s0c[(size_t)b * LC + i0 + rg + 4 * rr] = s;
    }
}

// ---------- prep_q: one pass over q -> qw16 = bf16(q*cqw), qT16 = bf16(q)^T, s1q ----
__global__ __launch_bounds__(256) void prep_q(
        const float* __restrict__ q, const float* __restrict__ cqw,
        const float* __restrict__ q_w, const float* __restrict__ bias,
        short* __restrict__ qw16, short* __restrict__ qT16,
        float* __restrict__ s1q) {
    __shared__ float T[64][65];
    int b = blockIdx.y, j0 = blockIdx.x * 64, t = threadIdx.x;
    int dd = t & 63, rg = t >> 6;
    float acc[16];
    #pragma unroll
    for (int i = 0; i < 16; ++i) acc[i] = 0.f;
    for (int dc = 0; dc < 4; ++dc) {
        float wv = cqw[dc * 64 + dd];
        float qwv = q_w[dc * 64 + dd];
        #pragma unroll
        for (int rr = 0; rr < 16; ++rr) {
            int r = rg + 4 * rr;
            float v = q[((size_t)b * LQ + j0 + r) * DD + dc * 64 + dd];
            qw16[((size_t)b * LQ + j0 + r) * DD + dc * 64 + dd] = f2b(v * wv);
            acc[rr] += v * qwv;
            T[dd][r] = v;
        }
        __syncthreads();
        int jj = t & 63;
        for (int dw = t >> 6; dw < 64; dw += 4)
            qT16[((size_t)b * DD + dc * 64 + dw) * LQ + j0 + jj] = f2b(T[dw][jj]);
        __syncthreads();
    }
    float bv = bias[0];
    #pragma unroll
    for (int rr = 0; rr < 16; ++rr) {
        float s = acc[rr];
        #pragma unroll
        for (int o = 32; o > 0; o >>= 1) s += __shfl_xor(s, o, 64);
        if (dd == 0) s1q[b * LQ + j0 + rg + 4 * rr] = s + bv;
    }
}

// ---------- k1: S tile [128 x 256] = c @ (q*cqw)^T + s0 + s1 (8 waves)
// writes: P1b [i][j] = bf16(row-softmax of S), STb [j][i] = bf16(col-masked S),
//         pm/ps column partial stats
__global__ __launch_bounds__(512) void k1_S(
        const short* __restrict__ c16, const short* __restrict__ qw16,
        const float* __restrict__ cmask, const float* __restrict__ qmask,
        const float* __restrict__ s0c, const float* __restrict__ s1q,
        short* __restrict__ P1b, short* __restrict__ STb,
        float* __restrict__ pm, float* __restrict__ ps) {
    __shared__ short As[128 * 64];
    __shared__ short Bs[256 * 64];
    __shared__ float rmLds[128 * 4];
    __shared__ float rsLds[128 * 4];
    __shared__ float rowCLds[128];
    int b  = blockIdx.y;
    int i0 = blockIdx.x * 128;
    int t = threadIdx.x;
    int l = t & 63, w = t >> 6;
    int wr = w >> 2, wc = w & 3;

    f32x4 acc[4][4];
    #pragma unroll
    for (int m = 0; m < 4; ++m)
        #pragma unroll
        for (int n = 0; n < 4; ++n) acc[m][n] = (f32x4){0.f, 0.f, 0.f, 0.f};

    const short* Ag = c16  + ((size_t)b * LC + i0) * DD;
    const short* Bg = qw16 + ((size_t)b * LQ) * DD;
    int lrow = l >> 3;                      // row within 8-row chunk
    int lcolsw = ((l & 7) ^ lrow) * 8;      // swizzled source col (bf16 elems)

    for (int kt = 0; kt < DD; kt += 64) {
        __syncthreads();
        #pragma unroll
        for (int r = 0; r < 2; ++r) {       // A: 16 chunks of 1KB
            int chunk = r * 8 + w;
            int row = chunk * 8 + lrow;
            gload_lds16(Ag + (size_t)row * DD + kt + lcolsw, As + chunk * 512);
        }
        #pragma unroll
        for (int r = 0; r < 4; ++r) {       // B: 32 chunks of 1KB
            int chunk = r * 8 + w;
            int row = chunk * 8 + lrow;
            gload_lds16(Bg + (size_t)row * DD + kt + lcolsw, Bs + chunk * 512);
        }
        __syncthreads();
        #pragma unroll
        for (int kf = 0; kf < 2; ++kf) {
            bf16x8 a[4], bb[4];
            #pragma unroll
            for (int m = 0; m < 4; ++m) {
                int row = wr * 64 + m * 16 + (l & 15);
                int byte = row * 128 + kf * 64 + (l >> 4) * 16;
                a[m] = *(const bf16x8*)((const char*)As + (byte ^ ((row & 7) << 4)));
            }
            #pragma unroll
            for (int n = 0; n < 4; ++n) {
                int row = wc * 64 + n * 16 + (l & 15);
                int byte = row * 128 + kf * 64 + (l >> 4) * 16;
                bb[n] = *(const bf16x8*)((const char*)Bs + (byte ^ ((row & 7) << 4)));
            }
            #pragma unroll
            for (int m = 0; m < 4; ++m)
                #pragma unroll
                for (int n = 0; n < 4; ++n)
                    acc[m][n] = MFMA16(a[m], bb[n], acc[m][n]);
        }
    }

    // ---- epilogue: add s0c + s1q, round to bf16 (acc := rounded S)
    float s1v[4], qmv[4], negq[4];
    #pragma unroll
    for (int n = 0; n < 4; ++n) {
        int j = wc * 64 + n * 16 + (l & 15);
        s1v[n] = s1q[b * LQ + j];
        qmv[n] = qmask[b * LQ + j];
        negq[n] = (1.f - qmv[n]) * NEGINF;
    }
    float s0r[4][4], cmr[4][4];
    #pragma unroll
    for (int m = 0; m < 4; ++m)
        #pragma unroll
        for (int reg = 0; reg < 4; ++reg) {
            int il = wr * 64 + m * 16 + (l >> 4) * 4 + reg;
            s0r[m][reg] = s0c[b * LC + i0 + il];
            cmr[m][reg] = cmask[b * LC + i0 + il];
        }
    #pragma unroll
    for (int m = 0; m < 4; ++m)
        #pragma unroll
        for (int n = 0; n < 4; ++n)
            #pragma unroll
            for (int reg = 0; reg < 4; ++reg) {
                float v = acc[m][n][reg] + s0r[m][reg] + s1v[n];
                acc[m][n][reg] = b2f(f2b(v));
            }

    // ---- column stats + STb [j][i] write (col-masked S, bf16)
    #pragma unroll
    for (int n = 0; n < 4; ++n) {
        int j = wc * 64 + n * 16 + (l & 15);
        float x2v[16];
        float mx = NEGINF;
        #pragma unroll
        for (int m = 0; m < 4; ++m)
            #pragma unroll
            for (int reg = 0; reg < 4; ++reg) {
                float cm = cmr[m][reg];
                float x2 = acc[m][n][reg] * cm + (1.f - cm) * NEGINF;
                x2v[m * 4 + reg] = x2;
                mx = fmaxf(mx, x2);
            }
        #pragma unroll
        for (int m = 0; m < 4; ++m) {
            short4 st;
            st.x = f2b(x2v[m * 4 + 0]);
            st.y = f2b(x2v[m * 4 + 1]);
            st.z = f2b(x2v[m * 4 + 2]);
            st.w = f2b(x2v[m * 4 + 3]);
            *(short4*)(STb + ((size_t)b * LQ + j) * (size_t)LC +
                       i0 + wr * 64 + m * 16 + (l >> 4) * 4) = st;
        }
        float ss = 0.f;
        #pragma unroll
        for (int e = 0; e < 16; ++e) ss += __expf(x2v[e] - mx);
        #pragma unroll
        for (int off = 16; off <= 32; off <<= 1) {
            float om = __shfl_xor(mx, off, 64);
            float os = __shfl_xor(ss, off, 64);
            float nm = fmaxf(mx, om);
            ss = ss * __expf(mx - nm) + os * __expf(om - nm);
            mx = nm;
        }
        if (l < 16) {
            size_t idx = ((size_t)b * 32 + blockIdx.x * 2 + wr) * LQ + wc * 64 + n * 16 + l;
            pm[idx] = mx;
            ps[idx] = ss;
        }
    }

    // ---- row stats: reduce over n (in-thread), l&15 (shfl), wc (LDS)
    #pragma unroll
    for (int m = 0; m < 4; ++m)
        #pragma unroll
        for (int reg = 0; reg < 4; ++reg) {
            float mx = NEGINF;
            #pragma unroll
            for (int n = 0; n < 4; ++n)
                mx = fmaxf(mx, fmaf(acc[m][n][reg], qmv[n], negq[n]));
            #pragma unroll
            for (int o = 1; o <= 8; o <<= 1) mx = fmaxf(mx, __shfl_xor(mx, o, 64));
            float ss = 0.f;
            #pragma unroll
            for (int n = 0; n < 4; ++n)
                ss += __expf(fmaf(acc[m][n][reg], qmv[n], negq[n]) - mx);
            #pragma unroll
            for (int o = 1; o <= 8; o <<= 1) ss += __shfl_xor(ss, o, 64);
            if ((l & 15) == 0) {
                int row = wr * 64 + m * 16 + (l >> 4) * 4 + reg;
                rmLds[row * 4 + wc] = mx;
                rsLds[row * 4 + wc] = ss;
            }
        }
    __syncthreads();
    if (t < 128) {
        float m0 = rmLds[t * 4 + 0], m1 = rmLds[t * 4 + 1];
        float m2 = rmLds[t * 4 + 2], m3 = rmLds[t * 4 + 3];
        float mm = fmaxf(fmaxf(m0, m1), fmaxf(m2, m3));
        float ss = rsLds[t * 4 + 0] * __expf(m0 - mm)
                 + rsLds[t * 4 + 1] * __expf(m1 - mm)
                 + rsLds[t * 4 + 2] * __expf(m2 - mm)
                 + rsLds[t * 4 + 3] * __expf(m3 - mm);
        rowCLds[t] = mm + logf(ss);
    }
    __syncthreads();

    // ---- P1b [i][j] write: finished row softmax, bf16
    float rC[4][4];
    #pragma unroll
    for (int m = 0; m < 4; ++m)
        #pragma unroll
        for (int reg = 0; reg < 4; ++reg)
            rC[m][reg] = rowCLds[wr * 64 + m * 16 + (l >> 4) * 4 + reg];
    #pragma unroll
    for (int m = 0; m < 4; ++m)
        #pragma unroll
        for (int n = 0; n < 4; ++n)
            #pragma unroll
            for (int reg = 0; reg < 4; ++reg) {
                float p = __expf(fmaf(acc[m][n][reg], qmv[n], negq[n]) - rC[m][reg]);
                int il = wr * 64 + m * 16 + (l >> 4) * 4 + reg;
                int j = wc * 64 + n * 16 + (l & 15);
                P1b[((size_t)b * LC + i0 + il) * LQ + j] = f2b(p);
            }
}

// ---------- kP: in-place STb[j][i] -> P2T[j][i] = bf16(exp(x2 - colC_j)) ----------
__global__ __launch_bounds__(256) void kP(
        short* __restrict__ STb,
        const float* __restrict__ pm, const float* __restrict__ ps) {
    __shared__ float colCs[16];
    int b = blockIdx.y, j0 = blockIdx.x * 16;
    int t = threadIdx.x;
    if (t < 16) {
        float m = NEGINF, s = 0.f;
        for (int ch = 0; ch < 32; ++ch) {
            float pmv = pm[((size_t)b * 32 + ch) * LQ + j0 + t];
            float psv = ps[((size_t)b * 32 + ch) * LQ + j0 + t];
            float mn = fmaxf(m, pmv);
            s = s * __expf(m - mn) + psv * __expf(pmv - mn);
            m = mn;
        }
        colCs[t] = m + logf(s);
    }
    __syncthreads();
    int r = t >> 4;
    int ib = (t & 15) * 8;
    float cC = colCs[r];
    short* row = STb + ((size_t)b * LQ + j0 + r) * (size_t)LC;
    #pragma unroll
    for (int it = 0; it < 16; ++it) {
        int i = ib + it * 128;
        bf16x8 v = *(const bf16x8*)(row + i);
        #pragma unroll
        for (int g = 0; g < 8; ++g)
            v[g] = f2b(__expf(b2f(v[g]) - cC));
        *(bf16x8*)(row + i) = v;
    }
}

// ---------- k3: LDS-free GEMM  A2CT[d][j] = sum_i cT16[d][i] * P2T[j][i] ----------
__global__ __launch_bounds__(256) void k3_A2C(
        const short* __restrict__ cT16, const short* __restrict__ P2T,
        short* __restrict__ A2CT) {
    int b = blockIdx.z;
    int d0 = blockIdx.x * 64;
    int j0 = blockIdx.y * 64;
    int t = threadIdx.x, l = t & 63, w = t >> 6;
    int wr = w >> 1, wc = w & 1;

    f32x4 acc[2][2];
    #pragma unroll
    for (int m = 0; m < 2; ++m)
        #pragma unroll
        for (int n = 0; n < 2; ++n) acc[m][n] = (f32x4){0.f, 0.f, 0.f, 0.f};

    const short* Ab = cT16 + ((size_t)b * DD + d0 + wr * 32 + (l & 15)) * (size_t)LC;
    const short* Bb = P2T  + ((size_t)b * LQ + j0 + wc * 32 + (l & 15)) * (size_t)LC;
    int ks0 = (l >> 4) * 8;

    #pragma unroll 4
    for (int kf = 0; kf < 64; ++kf) {
        int ki = kf * 32 + ks0;
        bf16x8 a[2], bb[2];
        #pragma unroll
        for (int m = 0; m < 2; ++m)
            a[m] = *(const bf16x8*)(Ab + (size_t)(m * 16) * LC + ki);
        #pragma unroll
        for (int n = 0; n < 2; ++n)
            bb[n] = *(const bf16x8*)(Bb + (size_t)(n * 16) * LC + ki);
        #pragma unroll
        for (int m = 0; m < 2; ++m)
            #pragma unroll
            for (int n = 0; n < 2; ++n)
                acc[m][n] = MFMA16(a[m], bb[n], acc[m][n]);
    }
    #pragma unroll
    for (int m = 0; m < 2; ++m)
        #pragma unroll
        for (int n = 0; n < 2; ++n)
            #pragma unroll
            for (int reg = 0; reg < 4; ++reg) {
                int d = d0 + wr * 32 + m * 16 + (l >> 4) * 4 + reg;
                int j = j0 + wc * 32 + n * 16 + (l & 15);
                A2CT[((size_t)b * DD + d) * LQ + j] = f2b(acc[m][n][reg]);
            }
}

// ---------- k4: pure GEMM  C2Q = P1@q, Q2C = P1@A2C + fused epilogue ----------
__global__ __launch_bounds__(256) void k4_out(
        const short* __restrict__ P1b, const short* __restrict__ qT16,
        const short* __restrict__ A2CT, const float* __restrict__ c,
        float* __restrict__ out) {
    int b = blockIdx.y, i0 = blockIdx.x * 64;
    int t = threadIdx.x, l = t & 63, w = t >> 6;
    int d0w = w * 64;

    f32x4 acc1[4][4], acc2[4][4];
    #pragma unroll
    for (int m = 0; m < 4; ++m)
        #pragma unroll
        for (int n = 0; n < 4; ++n) {
            acc1[m][n] = (f32x4){0.f, 0.f, 0.f, 0.f};
            acc2[m][n] = (f32x4){0.f, 0.f, 0.f, 0.f};
        }
    const short* Sr  = P1b  + ((size_t)b * LC + i0) * LQ;
    const short* qTb = qT16 + (size_t)b * DD * LQ;
    const short* aTb = A2CT + (size_t)b * DD * LQ;

    #pragma unroll 2
    for (int kf = 0; kf < 8; ++kf) {
        int j8 = kf * 32 + (l >> 4) * 8;
        bf16x8 a[4];
        #pragma unroll
        for (int m = 0; m < 4; ++m)
            a[m] = *(const bf16x8*)(Sr + (size_t)(m * 16 + (l & 15)) * LQ + j8);
        #pragma unroll
        for (int n = 0; n < 4; ++n) {
            int d = d0w + n * 16 + (l & 15);
            size_t off = (size_t)d * LQ + j8;
            bf16x8 bq = *(const bf16x8*)(qTb + off);
            bf16x8 ba = *(const bf16x8*)(aTb + off);
            #pragma unroll
            for (int m = 0; m < 4; ++m) {
                acc1[m][n] = MFMA16(a[m], bq, acc1[m][n]);
                acc2[m][n] = MFMA16(a[m], ba, acc2[m][n]);
            }
        }
    }
    #pragma unroll
    for (int m = 0; m < 4; ++m)
        #pragma unroll
        for (int n = 0; n < 4; ++n)
            #pragma unroll
            for (int reg = 0; reg < 4; ++reg) {
                int i = i0 + m * 16 + (l >> 4) * 4 + reg;
                int d = d0w + n * 16 + (l & 15);
                float cv = c[((size_t)b * LC + i) * DD + d];
                size_t ob = ((size_t)b * LC + i) * (size_t)(4 * DD);
                float v1 = acc1[m][n][reg], v2 = acc2[m][n][reg];
                out[ob + d]           = cv;
                out[ob + 256 + d]     = v1;
                out[ob + 512 + d]     = cv * v1;
                out[ob + 768 + d]     = cv * v2;
            }
}

extern "C" void kernel_launch(void* const* d_in, const int* in_sizes, int n_in,
                              void* d_out, int out_size, void* d_ws, size_t ws_size,
                              hipStream_t stream) {
    const float* c     = (const float*)d_in[0];
    const float* q     = (const float*)d_in[1];
    const float* cmask = (const float*)d_in[2];
    const float* qmask = (const float*)d_in[3];
    const float* cqw   = (const float*)d_in[4];
    const float* c_w   = (const float*)d_in[5];
    const float* q_w   = (const float*)d_in[6];
    const float* bias  = (const float*)d_in[7];
    float* out = (float*)d_out;

    char* w = (char*)d_ws;
    short* P1b   = (short*)(w);                  // 16,777,216 B  [i][j] P1 bf16
    short* STb   = (short*)(w + 16777216);       // 16,777,216 B  [j][i] -> P2T in place
    short* c16   = (short*)(w + 33554432);       // 16,777,216 B  [i][d]
    short* cT16  = (short*)(w + 50331648);       // 16,777,216 B  [d][i]
    short* qw16  = (short*)(w + 67108864);       //  2,097,152 B
    short* qT16  = (short*)(w + 69206016);       //  2,097,152 B
    short* A2CT  = (short*)(w + 71303168);       //  2,097,152 B
    float* s0c   = (float*)(w + 73400320);       //    131,072 B
    float* s1q   = (float*)(w + 73531392);       //     16,384 B
    float* pm    = (float*)(w + 73547776);       //    524,288 B
    float* ps    = (float*)(w + 74072064);       //    524,288 B (end 74,596,352)

    prep_c<<<dim3(LC / 64, NB), dim3(256), 0, stream>>>(c, c_w, c16, cT16, s0c);
    prep_q<<<dim3(LQ / 64, NB), dim3(256), 0, stream>>>(
        q, cqw, q_w, bias, qw16, qT16, s1q);
    k1_S<<<dim3(LC / 128, NB), dim3(512), 0, stream>>>(
        c16, qw16, cmask, qmask, s0c, s1q, P1b, STb, pm, ps);
    kP<<<dim3(LQ / 16, NB), dim3(256), 0, stream>>>(STb, pm, ps);
    k3_A2C<<<dim3(DD / 64, LQ / 64, NB), dim3(256), 0, stream>>>(cT16, STb, A2CT);
    k4_out<<<dim3(LC / 64, NB), dim3(256), 0, stream>>>(
        P1b, qT16, A2CT, c, out);
}

// Round 7
// 118.795 us; speedup vs baseline: 1.2345x; 1.2345x over previous
//
#include <hip/hip_runtime.h>
#include <hip/hip_bf16.h>

#define NB 16
#define LC 2048
#define LQ 256
#define DD 256
#define NEGINF -1e30f

typedef __attribute__((ext_vector_type(8))) short bf16x8;
typedef __attribute__((ext_vector_type(4))) float f32x4;

#define MFMA16(a, b, c) __builtin_amdgcn_mfma_f32_16x16x32_bf16((a), (b), (c), 0, 0, 0)

typedef const unsigned int __attribute__((address_space(1))) glb_u32;
typedef unsigned int __attribute__((address_space(3))) lds_u32;

__device__ __forceinline__ void gload_lds16(const void* g, void* l) {
    __builtin_amdgcn_global_load_lds((glb_u32*)g, (lds_u32*)l, 16, 0, 0);
}

__device__ __forceinline__ short f2b(float x) {
    unsigned u = __float_as_uint(x);
    unsigned r = (u + 0x7fffu + ((u >> 16) & 1u)) >> 16;
    return (short)r;
}
__device__ __forceinline__ float b2f(short s) {
    return __uint_as_float(((unsigned)(unsigned short)s) << 16);
}

// ---------- prep: fused. c-blocks: c16 + s0c. q-blocks: qw16/qT16/s1q ----------
#define NCB (NB * LC / 8)
__global__ __launch_bounds__(256) void prep(
        const float* __restrict__ c, const float* __restrict__ q,
        const float* __restrict__ c_w, const float* __restrict__ cqw,
        const float* __restrict__ q_w, const float* __restrict__ bias,
        short* __restrict__ c16, float* __restrict__ s0c,
        short* __restrict__ qw16, short* __restrict__ qT16,
        float* __restrict__ s1q) {
    __shared__ float T[64][65];
    int t = threadIdx.x;
    if (blockIdx.x < NCB) {
        int row = blockIdx.x * 8 + (t >> 5);
        int k = t & 31;
        const float* src = c + (size_t)row * DD + k * 8;
        float4 v0 = *(const float4*)(src);
        float4 v1 = *(const float4*)(src + 4);
        float4 w0 = *(const float4*)(c_w + k * 8);
        float4 w1 = *(const float4*)(c_w + k * 8 + 4);
        float s = v0.x * w0.x + v0.y * w0.y + v0.z * w0.z + v0.w * w0.w
                + v1.x * w1.x + v1.y * w1.y + v1.z * w1.z + v1.w * w1.w;
        #pragma unroll
        for (int o = 16; o > 0; o >>= 1) s += __shfl_xor(s, o, 64);
        if (k == 0) s0c[row] = s;
        ushort4 o0, o1;
        o0.x = (unsigned short)f2b(v0.x); o0.y = (unsigned short)f2b(v0.y);
        o0.z = (unsigned short)f2b(v0.z); o0.w = (unsigned short)f2b(v0.w);
        o1.x = (unsigned short)f2b(v1.x); o1.y = (unsigned short)f2b(v1.y);
        o1.z = (unsigned short)f2b(v1.z); o1.w = (unsigned short)f2b(v1.w);
        ushort4* dst = (ushort4*)(c16 + (size_t)row * DD + k * 8);
        dst[0] = o0;
        dst[1] = o1;
    } else {
        int idx = blockIdx.x - NCB;
        int b = idx >> 2, j0 = (idx & 3) * 64;
        int dd = t & 63, rg = t >> 6;
        float acc[16];
        #pragma unroll
        for (int i = 0; i < 16; ++i) acc[i] = 0.f;
        for (int dc = 0; dc < 4; ++dc) {
            float wv = cqw[dc * 64 + dd];
            float qwv = q_w[dc * 64 + dd];
            #pragma unroll
            for (int rr = 0; rr < 16; ++rr) {
                int r = rg + 4 * rr;
                float v = q[((size_t)b * LQ + j0 + r) * DD + dc * 64 + dd];
                qw16[((size_t)b * LQ + j0 + r) * DD + dc * 64 + dd] = f2b(v * wv);
                acc[rr] += v * qwv;
                T[dd][r] = v;
            }
            __syncthreads();
            int jj = t & 63;
            for (int dw = t >> 6; dw < 64; dw += 4)
                qT16[((size_t)b * DD + dc * 64 + dw) * LQ + j0 + jj] = f2b(T[dw][jj]);
            __syncthreads();
        }
        float bv = bias[0];
        #pragma unroll
        for (int rr = 0; rr < 16; ++rr) {
            float s = acc[rr];
            #pragma unroll
            for (int o = 32; o > 0; o >>= 1) s += __shfl_xor(s, o, 64);
            if (dd == 0) s1q[b * LQ + j0 + rg + 4 * rr] = s + bv;
        }
    }
}

// ---------- k1: S tile [128 x 256] = c @ (q*cqw)^T + s0 + s1 (8 waves)
// outputs: P1b [i][j] = bf16(finished row softmax), rowC, pm/ps col partials
__global__ __launch_bounds__(512) void k1_S(
        const short* __restrict__ c16, const short* __restrict__ qw16,
        const float* __restrict__ cmask, const float* __restrict__ qmask,
        const float* __restrict__ s0c, const float* __restrict__ s1q,
        short* __restrict__ P1b, float* __restrict__ rowC,
        float* __restrict__ pm, float* __restrict__ ps) {
    __shared__ short As[128 * 64];
    __shared__ short Bs[256 * 64];
    __shared__ float rmLds[128 * 4];
    __shared__ float rsLds[128 * 4];
    __shared__ float rowCLds[128];
    int b  = blockIdx.y;
    int i0 = blockIdx.x * 128;
    int t = threadIdx.x;
    int l = t & 63, w = t >> 6;
    int wr = w >> 2, wc = w & 3;

    f32x4 acc[4][4];
    #pragma unroll
    for (int m = 0; m < 4; ++m)
        #pragma unroll
        for (int n = 0; n < 4; ++n) acc[m][n] = (f32x4){0.f, 0.f, 0.f, 0.f};

    const short* Ag = c16  + ((size_t)b * LC + i0) * DD;
    const short* Bg = qw16 + ((size_t)b * LQ) * DD;
    int lrow = l >> 3;
    int lcolsw = ((l & 7) ^ lrow) * 8;

    for (int kt = 0; kt < DD; kt += 64) {
        __syncthreads();
        #pragma unroll
        for (int r = 0; r < 2; ++r) {
            int chunk = r * 8 + w;
            int row = chunk * 8 + lrow;
            gload_lds16(Ag + (size_t)row * DD + kt + lcolsw, As + chunk * 512);
        }
        #pragma unroll
        for (int r = 0; r < 4; ++r) {
            int chunk = r * 8 + w;
            int row = chunk * 8 + lrow;
            gload_lds16(Bg + (size_t)row * DD + kt + lcolsw, Bs + chunk * 512);
        }
        __syncthreads();
        #pragma unroll
        for (int kf = 0; kf < 2; ++kf) {
            bf16x8 a[4], bb[4];
            #pragma unroll
            for (int m = 0; m < 4; ++m) {
                int row = wr * 64 + m * 16 + (l & 15);
                int byte = row * 128 + kf * 64 + (l >> 4) * 16;
                a[m] = *(const bf16x8*)((const char*)As + (byte ^ ((row & 7) << 4)));
            }
            #pragma unroll
            for (int n = 0; n < 4; ++n) {
                int row = wc * 64 + n * 16 + (l & 15);
                int byte = row * 128 + kf * 64 + (l >> 4) * 16;
                bb[n] = *(const bf16x8*)((const char*)Bs + (byte ^ ((row & 7) << 4)));
            }
            #pragma unroll
            for (int m = 0; m < 4; ++m)
                #pragma unroll
                for (int n = 0; n < 4; ++n)
                    acc[m][n] = MFMA16(a[m], bb[n], acc[m][n]);
        }
    }

    // ---- epilogue: add s0c + s1q, round to bf16 (acc := rounded S)
    float s1v[4], qmv[4], negq[4];
    #pragma unroll
    for (int n = 0; n < 4; ++n) {
        int j = wc * 64 + n * 16 + (l & 15);
        s1v[n] = s1q[b * LQ + j];
        qmv[n] = qmask[b * LQ + j];
        negq[n] = (1.f - qmv[n]) * NEGINF;
    }
    float s0r[4][4], cmr[4][4];
    #pragma unroll
    for (int m = 0; m < 4; ++m)
        #pragma unroll
        for (int reg = 0; reg < 4; ++reg) {
            int il = wr * 64 + m * 16 + (l >> 4) * 4 + reg;
            s0r[m][reg] = s0c[b * LC + i0 + il];
            cmr[m][reg] = cmask[b * LC + i0 + il];
        }
    #pragma unroll
    for (int m = 0; m < 4; ++m)
        #pragma unroll
        for (int n = 0; n < 4; ++n)
            #pragma unroll
            for (int reg = 0; reg < 4; ++reg) {
                float v = acc[m][n][reg] + s0r[m][reg] + s1v[n];
                acc[m][n][reg] = b2f(f2b(v));
            }

    // ---- column-softmax partial stats (over 128 i-rows, c_mask applied)
    #pragma unroll
    for (int n = 0; n < 4; ++n) {
        float x2v[16];
        float mx = NEGINF;
        #pragma unroll
        for (int m = 0; m < 4; ++m)
            #pragma unroll
            for (int reg = 0; reg < 4; ++reg) {
                float cm = cmr[m][reg];
                float x2 = acc[m][n][reg] * cm + (1.f - cm) * NEGINF;
                x2v[m * 4 + reg] = x2;
                mx = fmaxf(mx, x2);
            }
        float ss = 0.f;
        #pragma unroll
        for (int e = 0; e < 16; ++e) ss += __expf(x2v[e] - mx);
        #pragma unroll
        for (int off = 16; off <= 32; off <<= 1) {
            float om = __shfl_xor(mx, off, 64);
            float os = __shfl_xor(ss, off, 64);
            float nm = fmaxf(mx, om);
            ss = ss * __expf(mx - nm) + os * __expf(om - nm);
            mx = nm;
        }
        if (l < 16) {
            size_t idx = ((size_t)b * 32 + blockIdx.x * 2 + wr) * LQ + wc * 64 + n * 16 + l;
            pm[idx] = mx;
            ps[idx] = ss;
        }
    }

    // ---- row-softmax stats: reduce over n (in-thread), l&15 (shfl), wc (LDS)
    #pragma unroll
    for (int m = 0; m < 4; ++m)
        #pragma unroll
        for (int reg = 0; reg < 4; ++reg) {
            float mx = NEGINF;
            #pragma unroll
            for (int n = 0; n < 4; ++n)
                mx = fmaxf(mx, fmaf(acc[m][n][reg], qmv[n], negq[n]));
            #pragma unroll
            for (int o = 1; o <= 8; o <<= 1) mx = fmaxf(mx, __shfl_xor(mx, o, 64));
            float ss = 0.f;
            #pragma unroll
            for (int n = 0; n < 4; ++n)
                ss += __expf(fmaf(acc[m][n][reg], qmv[n], negq[n]) - mx);
            #pragma unroll
            for (int o = 1; o <= 8; o <<= 1) ss += __shfl_xor(ss, o, 64);
            if ((l & 15) == 0) {
                int row = wr * 64 + m * 16 + (l >> 4) * 4 + reg;
                rmLds[row * 4 + wc] = mx;
                rsLds[row * 4 + wc] = ss;
            }
        }
    __syncthreads();
    if (t < 128) {
        float m0 = rmLds[t * 4 + 0], m1 = rmLds[t * 4 + 1];
        float m2 = rmLds[t * 4 + 2], m3 = rmLds[t * 4 + 3];
        float mm = fmaxf(fmaxf(m0, m1), fmaxf(m2, m3));
        float ss = rsLds[t * 4 + 0] * __expf(m0 - mm)
                 + rsLds[t * 4 + 1] * __expf(m1 - mm)
                 + rsLds[t * 4 + 2] * __expf(m2 - mm)
                 + rsLds[t * 4 + 3] * __expf(m3 - mm);
        float rc = mm + logf(ss);
        rowCLds[t] = rc;
        rowC[(size_t)b * LC + i0 + t] = rc;
    }
    __syncthreads();

    // ---- P1b [i][j]: finished row softmax, bf16
    float rCv[4][4];
    #pragma unroll
    for (int m = 0; m < 4; ++m)
        #pragma unroll
        for (int reg = 0; reg < 4; ++reg)
            rCv[m][reg] = rowCLds[wr * 64 + m * 16 + (l >> 4) * 4 + reg];
    #pragma unroll
    for (int m = 0; m < 4; ++m)
        #pragma unroll
        for (int n = 0; n < 4; ++n)
            #pragma unroll
            for (int reg = 0; reg < 4; ++reg) {
                float p = __expf(fmaf(acc[m][n][reg], qmv[n], negq[n]) - rCv[m][reg]);
                int il = wr * 64 + m * 16 + (l >> 4) * 4 + reg;
                int j = wc * 64 + n * 16 + (l & 15);
                P1b[((size_t)b * LC + i0 + il) * LQ + j] = f2b(p);
            }
}

// ---------- k3: split-K partials of A2CT[d,j] = sum_i c[i,d] * (w_i * P1[i,j]) ----
// w_i = cm_i * exp(rowC_i); column scale exp(-colC_j) applied in k3r.
#define K3S 72
__global__ __launch_bounds__(256) void k3_A2C(
        const short* __restrict__ c16, const short* __restrict__ P1b,
        const float* __restrict__ cmask, const float* __restrict__ rowC,
        float* __restrict__ p3) {
    __shared__ short As[128 * K3S];   // [d][i]
    __shared__ short Bs[128 * K3S];   // [j][i]
    int b  = blockIdx.z;
    int ks = blockIdx.y;
    int d0 = (blockIdx.x >> 1) * 128;
    int j0 = (blockIdx.x & 1) * 128;
    int t = threadIdx.x, l = t & 63, w = t >> 6;
    int wr = w >> 1, wc = w & 1;

    f32x4 acc[4][4];
    #pragma unroll
    for (int m = 0; m < 4; ++m)
        #pragma unroll
        for (int n = 0; n < 4; ++n) acc[m][n] = (f32x4){0.f, 0.f, 0.f, 0.f};

    int ii = t >> 2;            // 0..63 : i within K-step
    int c4 = (t & 3) * 8;       // 16B sub-chunk

    for (int k0 = ks * 512; k0 < ks * 512 + 512; k0 += 64) {
        __syncthreads();
        float wgt = cmask[b * LC + k0 + ii] * __expf(rowC[(size_t)b * LC + k0 + ii]);
        #pragma unroll
        for (int e = 0; e < 4; ++e) {
            int dpos = c4 + e * 32;   // 0..127
            bf16x8 av = *(const bf16x8*)(c16 +
                    ((size_t)(b * LC + k0 + ii)) * DD + d0 + dpos);
            #pragma unroll
            for (int g = 0; g < 8; ++g) As[(dpos + g) * K3S + ii] = av[g];

            int jpos = c4 + e * 32;
            bf16x8 p8 = *(const bf16x8*)(P1b +
                    ((size_t)(b * LC + k0 + ii)) * LQ + j0 + jpos);
            #pragma unroll
            for (int g = 0; g < 8; ++g)
                Bs[(jpos + g) * K3S + ii] = f2b(b2f(p8[g]) * wgt);
        }
        __syncthreads();
        #pragma unroll
        for (int kf = 0; kf < 2; ++kf) {
            bf16x8 a[4], bb[4];
            #pragma unroll
            for (int m = 0; m < 4; ++m) {
                int row = wr * 64 + m * 16 + (l & 15);
                a[m] = *(const bf16x8*)((const char*)As +
                        row * (K3S * 2) + kf * 64 + (l >> 4) * 16);
            }
            #pragma unroll
            for (int n = 0; n < 4; ++n) {
                int row = wc * 64 + n * 16 + (l & 15);
                bb[n] = *(const bf16x8*)((const char*)Bs +
                        row * (K3S * 2) + kf * 64 + (l >> 4) * 16);
            }
            #pragma unroll
            for (int m = 0; m < 4; ++m)
                #pragma unroll
                for (int n = 0; n < 4; ++n)
                    acc[m][n] = MFMA16(a[m], bb[n], acc[m][n]);
        }
    }
    float* P = p3 + (((size_t)b * 4 + ks) * 4 + blockIdx.x) * 16384;
    #pragma unroll
    for (int m = 0; m < 4; ++m)
        #pragma unroll
        for (int n = 0; n < 4; ++n)
            #pragma unroll
            for (int reg = 0; reg < 4; ++reg) {
                int ld = wr * 64 + m * 16 + (l >> 4) * 4 + reg;
                int lj = wc * 64 + n * 16 + (l & 15);
                P[ld * 128 + lj] = acc[m][n][reg];
            }
}

// ---------- k3r: reduce 4 K-splits, apply exp(-colC_j), write bf16 A2CT ----------
__global__ __launch_bounds__(256) void k3r_reduce(
        const float* __restrict__ p3,
        const float* __restrict__ pm, const float* __restrict__ ps,
        short* __restrict__ A2CT) {
    __shared__ float colCs[256];
    int b = blockIdx.y;
    int t = threadIdx.x;
    {   // colC for j = t (all 256 j needed by every block)
        float m = NEGINF, s = 0.f;
        for (int ch = 0; ch < 32; ++ch) {
            float pmv = pm[((size_t)b * 32 + ch) * LQ + t];
            float psv = ps[((size_t)b * 32 + ch) * LQ + t];
            float mn = fmaxf(m, pmv);
            s = s * __expf(m - mn) + psv * __expf(pmv - mn);
            m = mn;
        }
        colCs[t] = m + logf(s);
    }
    __syncthreads();
    int linear = blockIdx.x * 256 + t;   // 0..16383
    int d = linear >> 6;
    int j4 = (linear & 63) * 4;
    int tile = (d >> 7) * 2 + (j4 >> 7);
    int ld = d & 127, lj = j4 & 127;
    const float* base = p3 + (((size_t)b * 4) * 4 + tile) * 16384 + ld * 128 + lj;
    float4 s = {0.f, 0.f, 0.f, 0.f};
    #pragma unroll
    for (int ks = 0; ks < 4; ++ks) {
        float4 v = *(const float4*)(base + (size_t)ks * 4 * 16384);
        s.x += v.x; s.y += v.y; s.z += v.z; s.w += v.w;
    }
    s.x *= __expf(-colCs[j4 + 0]);
    s.y *= __expf(-colCs[j4 + 1]);
    s.z *= __expf(-colCs[j4 + 2]);
    s.w *= __expf(-colCs[j4 + 3]);
    short4 o;
    o.x = f2b(s.x); o.y = f2b(s.y); o.z = f2b(s.z); o.w = f2b(s.w);
    *(short4*)(A2CT + ((size_t)b * DD + d) * LQ + j4) = o;
}

// ---------- k4: pure GEMM  C2Q = P1@q, Q2C = P1@A2C + fused epilogue ----------
__global__ __launch_bounds__(256) void k4_out(
        const short* __restrict__ P1b, const short* __restrict__ qT16,
        const short* __restrict__ A2CT, const float* __restrict__ c,
        float* __restrict__ out) {
    int b = blockIdx.y, i0 = blockIdx.x * 64;
    int t = threadIdx.x, l = t & 63, w = t >> 6;
    int d0w = w * 64;

    f32x4 acc1[4][4], acc2[4][4];
    #pragma unroll
    for (int m = 0; m < 4; ++m)
        #pragma unroll
        for (int n = 0; n < 4; ++n) {
            acc1[m][n] = (f32x4){0.f, 0.f, 0.f, 0.f};
            acc2[m][n] = (f32x4){0.f, 0.f, 0.f, 0.f};
        }
    const short* Sr  = P1b  + ((size_t)b * LC + i0) * LQ;
    const short* qTb = qT16 + (size_t)b * DD * LQ;
    const short* aTb = A2CT + (size_t)b * DD * LQ;

    #pragma unroll 2
    for (int kf = 0; kf < 8; ++kf) {
        int j8 = kf * 32 + (l >> 4) * 8;
        bf16x8 a[4];
        #pragma unroll
        for (int m = 0; m < 4; ++m)
            a[m] = *(const bf16x8*)(Sr + (size_t)(m * 16 + (l & 15)) * LQ + j8);
        #pragma unroll
        for (int n = 0; n < 4; ++n) {
            int d = d0w + n * 16 + (l & 15);
            size_t off = (size_t)d * LQ + j8;
            bf16x8 bq = *(const bf16x8*)(qTb + off);
            bf16x8 ba = *(const bf16x8*)(aTb + off);
            #pragma unroll
            for (int m = 0; m < 4; ++m) {
                acc1[m][n] = MFMA16(a[m], bq, acc1[m][n]);
                acc2[m][n] = MFMA16(a[m], ba, acc2[m][n]);
            }
        }
    }
    #pragma unroll
    for (int m = 0; m < 4; ++m)
        #pragma unroll
        for (int n = 0; n < 4; ++n)
            #pragma unroll
            for (int reg = 0; reg < 4; ++reg) {
                int i = i0 + m * 16 + (l >> 4) * 4 + reg;
                int d = d0w + n * 16 + (l & 15);
                float cv = c[((size_t)b * LC + i) * DD + d];
                size_t ob = ((size_t)b * LC + i) * (size_t)(4 * DD);
                float v1 = acc1[m][n][reg], v2 = acc2[m][n][reg];
                out[ob + d]           = cv;
                out[ob + 256 + d]     = v1;
                out[ob + 512 + d]     = cv * v1;
                out[ob + 768 + d]     = cv * v2;
            }
}

extern "C" void kernel_launch(void* const* d_in, const int* in_sizes, int n_in,
                              void* d_out, int out_size, void* d_ws, size_t ws_size,
                              hipStream_t stream) {
    const float* c     = (const float*)d_in[0];
    const float* q     = (const float*)d_in[1];
    const float* cmask = (const float*)d_in[2];
    const float* qmask = (const float*)d_in[3];
    const float* cqw   = (const float*)d_in[4];
    const float* c_w   = (const float*)d_in[5];
    const float* q_w   = (const float*)d_in[6];
    const float* bias  = (const float*)d_in[7];
    float* out = (float*)d_out;

    char* w = (char*)d_ws;
    short* P1b   = (short*)(w);                  // 16,777,216 B  [i][j]
    short* c16   = (short*)(w + 16777216);       // 16,777,216 B  [i][d]
    short* qw16  = (short*)(w + 33554432);       //  2,097,152 B
    short* qT16  = (short*)(w + 35651584);       //  2,097,152 B
    short* A2CT  = (short*)(w + 37748736);       //  2,097,152 B
    float* s0c   = (float*)(w + 39845888);       //    131,072 B
    float* s1q   = (float*)(w + 39976960);       //     16,384 B
    float* pm    = (float*)(w + 39993344);       //    524,288 B
    float* ps    = (float*)(w + 40517632);       //    524,288 B
    float* rowC  = (float*)(w + 41041920);       //    131,072 B
    float* p3    = (float*)(w + 41172992);       // 16,777,216 B (end 57,950,208)

    prep<<<dim3(NCB + NB * LQ / 64), dim3(256), 0, stream>>>(
        c, q, c_w, cqw, q_w, bias, c16, s0c, qw16, qT16, s1q);
    k1_S<<<dim3(LC / 128, NB), dim3(512), 0, stream>>>(
        c16, qw16, cmask, qmask, s0c, s1q, P1b, rowC, pm, ps);
    k3_A2C<<<dim3(4, 4, NB), dim3(256), 0, stream>>>(
        c16, P1b, cmask, rowC, p3);
    k3r_reduce<<<dim3(64, NB), dim3(256), 0, stream>>>(p3, pm, ps, A2CT);
    k4_out<<<dim3(LC / 64, NB), dim3(256), 0, stream>>>(
        P1b, qT16, A2CT, c, out);
}